// Round 12
// baseline (38033.856 us; speedup 1.0000x reference)
//
#include <hip/hip_runtime.h>
#include <hip/hip_bf16.h>

// LSTM T=2048, B=64, D=512, H=512.
// R12: 32 worker blocks x 512 thr (8 waves = 2 col-sets x 4 M-groups; block
// owns hidden cols [16b,16b+16)). Fewer sync endpoints: 32 flags = ONE 128B
// line; skew = max-of-32 (was 64). W in 256 VGPRs/lane via 2-pass LDS staging.
// h exchange: 2-slot bf16 ring + per-block flag, sc1 atomics (R5/R11 proven).
// Wave-0 polls (4 free tries then s_sleep(2)), LDS-broadcasts to waves 1-7.
// Consumer-side out[t-1] writes (R5-proven), x-prefetch after flag release.
// Heaters (224 blocks) hold DPM clocks with quiet poll (R11). No RMW polling
// (R6), no tagged-data exchange (R7/R10), no unverified cache ops (R9).

#define T_N 2048
#define B_N 64
#define D_N 512
#define H_N 512
#define NBLK 32
#define NHEAT 224
#define NTHR 512
#define BH (B_N * H_N)

#define STACK_ELEMS ((size_t)T_N * B_N * H_N)   // 67108864
#define HT_OFF STACK_ELEMS
#define CT_OFF (STACK_ELEMS + (size_t)B_N * H_N)

// ws layout (bytes)
#define WS_DONE 0
#define WS_FLAGS 1024            // u32 flags[32] (per-block), one 128B line
#define WS_RING 32768            // 2 slots x 64KB bf16 [slot][prod32][row64][col16]
#define WS_XB 262144

typedef __attribute__((ext_vector_type(4))) float f32x4;
typedef __attribute__((ext_vector_type(8))) short bf16x8;

__device__ __forceinline__ unsigned short f2bf(float f) {
  union { __hip_bfloat16 h; unsigned short u; } u;
  u.h = __float2bfloat16(f);
  return u.u;
}
__device__ __forceinline__ float bf2f(unsigned short us) {
  union { unsigned u32; float f; } x;
  x.u32 = ((unsigned)us) << 16;
  return x.f;
}
__device__ __forceinline__ float sigf(float x) { return 1.0f / (1.0f + __expf(-x)); }
__device__ __forceinline__ float tanhfast(float x) { return 1.0f - 2.0f / (__expf(2.0f * x) + 1.0f); }

__global__ void init_ws_kernel(unsigned* ws32) {
  int i = blockIdx.x * blockDim.x + threadIdx.x;
  if (i < 65536) ws32[i] = 0u;  // zero done + flags + ring (256 KB)
}

__global__ void xconv_kernel(const float* __restrict__ X, unsigned short* __restrict__ Xb) {
  size_t i = ((size_t)blockIdx.x * blockDim.x + threadIdx.x) * 8;
  float4 v0 = *(const float4*)(X + i);
  float4 v1 = *(const float4*)(X + i + 4);
  bf16x8 o;
  o[0] = (short)f2bf(v0.x); o[1] = (short)f2bf(v0.y);
  o[2] = (short)f2bf(v0.z); o[3] = (short)f2bf(v0.w);
  o[4] = (short)f2bf(v1.x); o[5] = (short)f2bf(v1.y);
  o[6] = (short)f2bf(v1.z); o[7] = (short)f2bf(v1.w);
  *(bf16x8*)(Xb + i) = o;
}

__device__ __forceinline__ void load_x_tile(const unsigned short* Xb, const float* X,
                                            int t, int arow, int kg, bf16x8 (&xa)[16]) {
  if (Xb) {
    const unsigned short* xp = Xb + ((size_t)t * B_N + arow) * D_N + kg;
#pragma unroll
    for (int kk = 0; kk < 16; ++kk) xa[kk] = *(const bf16x8*)(xp + kk * 32);
  } else {
    const float* xp = X + ((size_t)t * B_N + arow) * D_N + kg;
#pragma unroll
    for (int kk = 0; kk < 16; ++kk) {
      float4 v0 = *(const float4*)(xp + kk * 32);
      float4 v1 = *(const float4*)(xp + kk * 32 + 4);
      bf16x8 a;
      a[0] = (short)f2bf(v0.x); a[1] = (short)f2bf(v0.y);
      a[2] = (short)f2bf(v0.z); a[3] = (short)f2bf(v0.w);
      a[4] = (short)f2bf(v1.x); a[5] = (short)f2bf(v1.y);
      a[6] = (short)f2bf(v1.z); a[7] = (short)f2bf(v1.w);
      xa[kk] = a;
    }
  }
}

__global__ __launch_bounds__(NTHR, 1) void lstm_kernel(
    const float* __restrict__ X, const unsigned short* __restrict__ Xb,
    const float* __restrict__ Wf, const float* __restrict__ bF,
    const float* __restrict__ Wi, const float* __restrict__ bI,
    const float* __restrict__ Wg, const float* __restrict__ bG,
    const float* __restrict__ Wo, const float* __restrict__ bO,
    unsigned char* wsb, float* __restrict__ out) {
  __shared__ unsigned short Wl[32768];  // 64 KB staging (2 passes)
  __shared__ unsigned sReady;           // step-ready broadcast (wave0 -> 1..7)
  __shared__ int hstop;                 // heater exit broadcast

  const int tid = threadIdx.x;
  const int blk = blockIdx.x;
  const int lane = tid & 63;

  if (blk >= NBLK) {
    // ------- HEATER: hold DPM clocks; 1 thread polls done every ~27us -------
    if (tid == 0) *(volatile int*)&hstop = 0;
    __syncthreads();
    const unsigned* dp = (const unsigned*)(wsb + WS_DONE);
    float a = 1.0f + (float)(blk * NTHR + tid) * 1e-7f;
    const float hm = 0.99993f, hc = 1e-8f;
    for (long i = 0;; ++i) {
#pragma unroll
      for (int j = 0; j < 512; ++j) a = __builtin_fmaf(a, hm, hc);
      if (tid == 0 && (i & 63) == 0) {
        unsigned d = __hip_atomic_load(dp, __ATOMIC_RELAXED, __HIP_MEMORY_SCOPE_AGENT);
        if (d >= (unsigned)NBLK) *(volatile int*)&hstop = 1;
      }
      if (*(volatile int*)&hstop) break;
      if (i > (1l << 21)) break;  // backstop: no hang
    }
    asm volatile("" :: "v"(a));
    return;
  }

  // ---------------- WORKER ----------------
  const int w = tid >> 6;        // wave 0..7
  const int cs = w >> 2;         // col-set 0/1 (8 hidden cols each)
  const int m = w & 3;           // M-group -> A rows 16m..16m+15
  const int l16 = lane & 15;
  const int g16 = lane >> 4;
  const int cc = l16 & 7;
  const bool lo = (l16 < 8);

  if (tid == 0) *(volatile unsigned*)&sReady = 0u;

  // ---- stage W in 2 passes (col-subset p = [16*blk + 8p, +8)); wave set
  // cs==p grabs its fragments. Fragment-linear layout (conflict-free b128).
  bf16x8 wb0[32], wb1[32];
  for (int p = 0; p < 2; ++p) {
    __syncthreads();
    for (int idx = tid; idx < 32768; idx += NTHR) {
      int k = idx >> 5;
      int cl = idx & 31;
      const float* wsrc = (cl < 8) ? Wf : (cl < 16) ? Wi : (cl < 24) ? Wg : Wo;
      float v = wsrc[(size_t)k * H_N + 16 * blk + 8 * p + (cl & 7)];
      int pos = ((k >> 5) * 1024) + ((cl >> 4) * 512) + (((k >> 3) & 3) * 128) + ((cl & 15) * 8) + (k & 7);
      Wl[pos] = f2bf(v);
    }
    __syncthreads();
    if (cs == p) {
#pragma unroll
      for (int K = 0; K < 32; ++K) {
        wb0[K] = *(const bf16x8*)&Wl[K * 1024 + lane * 8];
        wb1[K] = *(const bf16x8*)&Wl[K * 1024 + 512 + lane * 8];
      }
    }
  }

  const int c0w = 16 * blk + 8 * cs;
  const float bias0 = lo ? bF[c0w + cc] : bI[c0w + cc];
  const float bias1 = lo ? bG[c0w + cc] : bO[c0w + cc];

  const int arow = 16 * m + l16;
  const int kg = 8 * g16;
  const bool owner = (cs == 0) && ((arow >> 1) == blk);  // rows 2blk, 2blk+1

  unsigned* flags = (unsigned*)(wsb + WS_FLAGS);
  float cst[4] = {0.f, 0.f, 0.f, 0.f};
  float hT_local[4] = {0.f, 0.f, 0.f, 0.f};

  bf16x8 xa[16];
  load_x_tile(Xb, X, 0, arow, kg, xa);

  for (int t = 0; t < T_N; ++t) {
    const int slotR = (t + 1) & 1;
    const int slotW = t & 1;

    // ---- x MFMAs (prefetched xa)
    f32x4 x0a = {0,0,0,0}, x0b = {0,0,0,0}, x1a = {0,0,0,0}, x1b = {0,0,0,0};
#pragma unroll
    for (int kk = 0; kk < 8; ++kk) {
      x0a = __builtin_amdgcn_mfma_f32_16x16x32_bf16(xa[kk], wb0[kk], x0a, 0, 0, 0);
      x1a = __builtin_amdgcn_mfma_f32_16x16x32_bf16(xa[kk], wb1[kk], x1a, 0, 0, 0);
    }
#pragma unroll
    for (int kk = 8; kk < 16; ++kk) {
      x0b = __builtin_amdgcn_mfma_f32_16x16x32_bf16(xa[kk], wb0[kk], x0b, 0, 0, 0);
      x1b = __builtin_amdgcn_mfma_f32_16x16x32_bf16(xa[kk], wb1[kk], x1b, 0, 0, 0);
    }

    // ---- wait for h_{t-1}: wave 0 polls the single 128B flag line;
    // waves 1-7 spin on LDS (zero global traffic).
    if (t > 0) {
      const unsigned tgt = (unsigned)t;
      if (w == 0) {
        long guard = 0;
        for (;;) {
          unsigned fv = __hip_atomic_load(flags + (lane & 31), __ATOMIC_RELAXED, __HIP_MEMORY_SCOPE_AGENT);
          if (__all((int)(fv >= tgt))) break;
          if (++guard > 4) __builtin_amdgcn_s_sleep(2);
          if (guard > (1l << 18)) break;  // bounded bail-out: no timeout
        }
        if (lane == 0) *(volatile unsigned*)&sReady = tgt;
      } else {
        long guard = 0;
        while (*(volatile unsigned*)&sReady < tgt) {
          if (++guard > (1l << 24)) break;  // bounded bail-out
        }
      }
    }

    // ---- 32 h-loads, one batch. Ring [slot][prod(32)][row(64)][col(16)] bf16.
    // Lane's kk-th 16B comes from producer 2kk+(g16>>1), offset 8*(g16&1) cols.
    unsigned long long hq0[16], hq1[16];
    {
      const unsigned char* hb = wsb + WS_RING + (size_t)slotR * 65536;
      const unsigned char* hrow = hb + arow * 32 + (g16 & 1) * 16;
#pragma unroll
      for (int kk = 0; kk < 16; ++kk) {
        const unsigned long long* hp =
            (const unsigned long long*)(hrow + (size_t)(2 * kk + (g16 >> 1)) * 2048);
        hq0[kk] = __hip_atomic_load(hp, __ATOMIC_RELAXED, __HIP_MEMORY_SCOPE_AGENT);
        hq1[kk] = __hip_atomic_load(hp + 1, __ATOMIC_RELAXED, __HIP_MEMORY_SCOPE_AGENT);
      }
    }

    // ---- h MFMAs (t=0 reads zeroed ring -> adds 0, correct)
    f32x4 h0a = {0,0,0,0}, h0b = {0,0,0,0}, h1a = {0,0,0,0}, h1b = {0,0,0,0};
#pragma unroll
    for (int kk = 0; kk < 8; ++kk) {
      union { unsigned long long q[2]; bf16x8 v; } u;
      u.q[0] = hq0[kk]; u.q[1] = hq1[kk];
      h0a = __builtin_amdgcn_mfma_f32_16x16x32_bf16(u.v, wb0[16 + kk], h0a, 0, 0, 0);
      h1a = __builtin_amdgcn_mfma_f32_16x16x32_bf16(u.v, wb1[16 + kk], h1a, 0, 0, 0);
    }
#pragma unroll
    for (int kk = 8; kk < 16; ++kk) {
      union { unsigned long long q[2]; bf16x8 v; } u;
      u.q[0] = hq0[kk]; u.q[1] = hq1[kk];
      h0b = __builtin_amdgcn_mfma_f32_16x16x32_bf16(u.v, wb0[16 + kk], h0b, 0, 0, 0);
      h1b = __builtin_amdgcn_mfma_f32_16x16x32_bf16(u.v, wb1[16 + kk], h1b, 0, 0, 0);
    }
    f32x4 m0v = (x0a + x0b) + (h0a + h0b);
    f32x4 m1v = (x1a + x1b) + (h1a + h1b);

    // ---- gates + cell update (hv identical in lo/hi partner lanes)
    float hv[4];
#pragma unroll
    for (int r = 0; r < 4; ++r) {
      float m0 = m0v[r] + bias0;
      float m1 = m1v[r] + bias1;
      float p0 = __shfl_xor(m0, 8, 64);
      float p1 = __shfl_xor(m1, 8, 64);
      float fv = lo ? m0 : p0;
      float iv = lo ? p0 : m0;
      float gv = lo ? m1 : p1;
      float ov = lo ? p1 : m1;
      float f = sigf(fv), i = sigf(iv), g = tanhfast(gv), o = sigf(ov);
      float c = f * cst[r] + i * g;
      cst[r] = c;
      hv[r] = o * tanhfast(c);
    }

    // ---- publish h_t into this block's 2KB ring chunk (lo even-cc lanes)
    {
      unsigned char* rb = wsb + WS_RING + (size_t)slotW * 65536 + (size_t)blk * 2048;
#pragma unroll
      for (int r = 0; r < 4; ++r) {
        int row = 16 * m + 4 * g16 + r;
        unsigned short hb16 = f2bf(hv[r]);
        unsigned opp = __shfl_xor((unsigned)hb16, 1, 64);
        if (lo && (cc & 1) == 0) {
          unsigned pack = (unsigned)hb16 | (opp << 16);
          __hip_atomic_store((unsigned*)(rb + row * 32 + (8 * cs + cc) * 2), pack,
                             __ATOMIC_RELAXED, __HIP_MEMORY_SCOPE_AGENT);
        }
      }
    }

    // ---- release: all waves drain, then ONE per-block flag store
    asm volatile("s_waitcnt vmcnt(0)" ::: "memory");
    __syncthreads();
    if (tid == 0) {
      __hip_atomic_store(flags + blk, (unsigned)(t + 1),
                         __ATOMIC_RELAXED, __HIP_MEMORY_SCOPE_AGENT);
    }

    // ---- prefetch next x tile (completes during next step)
    if (t + 1 < T_N) load_x_tile(Xb, X, t + 1, arow, kg, xa);

    // ---- out[t-1] full-row write (consumer side, off critical path):
    // owner lanes (8 per block) cover rows 2blk, 2blk+1 x all 512 cols.
    if (owner && t > 0) {
      float* oprev = out + (size_t)(t - 1) * BH + (size_t)arow * H_N + kg;
#pragma unroll
      for (int kk = 0; kk < 16; ++kk) {
        union { unsigned long long q[2]; bf16x8 v; } u;
        u.q[0] = hq0[kk]; u.q[1] = hq1[kk];
        float4 f0, f1;
        f0.x = bf2f((unsigned short)u.v[0]); f0.y = bf2f((unsigned short)u.v[1]);
        f0.z = bf2f((unsigned short)u.v[2]); f0.w = bf2f((unsigned short)u.v[3]);
        f1.x = bf2f((unsigned short)u.v[4]); f1.y = bf2f((unsigned short)u.v[5]);
        f1.z = bf2f((unsigned short)u.v[6]); f1.w = bf2f((unsigned short)u.v[7]);
        *(float4*)(oprev + kk * 32) = f0;
        *(float4*)(oprev + kk * 32 + 4) = f1;
      }
    }

    // ---- final step: producer writes out[T-1] slice + keeps hT
    if (t == T_N - 1) {
      float* obase = out + (size_t)t * BH;
#pragma unroll
      for (int r = 0; r < 4; ++r) {
        int row = 16 * m + 4 * g16 + r;
        if (lo) obase[(size_t)row * H_N + c0w + cc] = hv[r];
        hT_local[r] = hv[r];
      }
    }
  }

  // ---- final hT / cT
  if (lo) {
#pragma unroll
    for (int r = 0; r < 4; ++r) {
      int row = 16 * m + 4 * g16 + r;
      out[HT_OFF + (size_t)row * H_N + c0w + cc] = hT_local[r];
      out[CT_OFF + (size_t)row * H_N + c0w + cc] = cst[r];
    }
  }
  __syncthreads();
  if (tid == 0)
    __hip_atomic_fetch_add((unsigned*)(wsb + WS_DONE), 1u,
                           __ATOMIC_RELAXED, __HIP_MEMORY_SCOPE_AGENT);
}

extern "C" void kernel_launch(void* const* d_in, const int* in_sizes, int n_in,
                              void* d_out, int out_size, void* d_ws, size_t ws_size,
                              hipStream_t stream) {
  const float* X  = (const float*)d_in[0];
  const float* Wf = (const float*)d_in[1];
  const float* bF = (const float*)d_in[2];
  const float* Wi = (const float*)d_in[3];
  const float* bI = (const float*)d_in[4];
  const float* Wg = (const float*)d_in[5];
  const float* bG = (const float*)d_in[6];
  const float* Wo = (const float*)d_in[7];
  const float* bO = (const float*)d_in[8];
  float* out = (float*)d_out;

  unsigned char* ws = (unsigned char*)d_ws;
  const size_t need_xb = WS_XB + (size_t)T_N * B_N * D_N * 2;  // ~129 MB
  unsigned short* Xb = (ws_size >= need_xb) ? (unsigned short*)(ws + WS_XB) : nullptr;

  init_ws_kernel<<<dim3(256), dim3(256), 0, stream>>>((unsigned*)ws);
  if (Xb) {
    xconv_kernel<<<dim3((T_N * B_N * D_N) / 8 / 256), dim3(256), 0, stream>>>(X, Xb);
  }
  lstm_kernel<<<dim3(NBLK + NHEAT), dim3(NTHR), 0, stream>>>(
      X, Xb, Wf, bF, Wi, bI, Wg, bG, Wo, bO, ws, out);
}